// Round 1
// baseline (11537.175 us; speedup 1.0000x reference)
//
#include <hip/hip_runtime.h>
#include <stdint.h>
#include <stddef.h>

// ---------------------------------------------------------------------------
// BiLSTM seq2seq (Bahdanau attention) on MI355X.
// B=32, T_src=T_tgt=64, E=512, H=512 (enc dir), dec hidden 2H=1024, V=32000.
// This revision: persistent-kernel recurrences. Encoder = ONE kernel (64
// blocks, 64 steps, device-scope grid barrier). Decoder = ONE kernel (80
// blocks, 64 steps x 3 phases). Removes ~256 serial kernel launches and
// makes per-block weight slices L2-resident (fixed block<->CU mapping).
// ---------------------------------------------------------------------------

using u16 = unsigned short;
using u32 = unsigned int;
using short8 = __attribute__((ext_vector_type(8))) short;  // 8 bf16 (4 VGPRs)
using f32x4  = __attribute__((ext_vector_type(4))) float;  // MFMA acc

#define DEVI __device__ __forceinline__

DEVI float bf2f(u16 u){ union{u32 i; float f;} v; v.i = ((u32)u)<<16; return v.f; }
DEVI u16 f2bf(float f){ union{float f; u32 i;} v; v.f = f;
  u32 r = (v.i + 0x7fffu + ((v.i>>16)&1u)) >> 16; return (u16)r; }
DEVI float sigf(float x){ x = fminf(fmaxf(x,-30.f),30.f); return 1.f/(1.f+__expf(-x)); }
DEVI float tanh_f(float x){ float ax = fminf(fabsf(x),15.f);
  float e = __expf(2.f*ax); float t = (e-1.f)/(e+1.f); return x<0.f? -t : t; }

DEVI f32x4 mfma16(short8 a, short8 b, f32x4 c){
  return __builtin_amdgcn_mfma_f32_16x16x32_bf16(a,b,c,0,0,0);
}
DEVI short8 ld8(const u16* p){ return *(const short8*)p; }

DEVI void storeC(float* C, size_t i, float v){ C[i]=v; }
DEVI void storeC(u16*   C, size_t i, float v){ C[i]=f2bf(v); }

// ---------------------------------------------------------------------------
// Device-scope sense-reversing grid barrier. Requires all blocks co-resident
// (grid <= 1 block/CU with declared __launch_bounds__; MI355X has 256 CUs).
// bar[0] = arrival count, bar[1] = generation.
// ---------------------------------------------------------------------------
DEVI void gbar(unsigned* bar, unsigned nb){
  __syncthreads();
  if(threadIdx.x==0){
    __threadfence();   // publish this block's writes (agent scope, L2 wb)
    unsigned g = __hip_atomic_load(bar+1, __ATOMIC_RELAXED, __HIP_MEMORY_SCOPE_AGENT);
    unsigned a = __hip_atomic_fetch_add(bar, 1u, __ATOMIC_ACQ_REL, __HIP_MEMORY_SCOPE_AGENT);
    if(a == nb-1u){
      __hip_atomic_store(bar, 0u, __ATOMIC_RELAXED, __HIP_MEMORY_SCOPE_AGENT);
      __hip_atomic_fetch_add(bar+1, 1u, __ATOMIC_ACQ_REL, __HIP_MEMORY_SCOPE_AGENT);
    } else {
      while(__hip_atomic_load(bar+1, __ATOMIC_ACQUIRE, __HIP_MEMORY_SCOPE_AGENT) == g)
        __builtin_amdgcn_s_sleep(2);
    }
    __threadfence();
  }
  __syncthreads();
}

__global__ void zero_bar(unsigned* __restrict__ bar){
  if(threadIdx.x < 2) bar[threadIdx.x] = 0u;
}

// ---------------------------------------------------------------------------
// Embedding gather: emb_src[t*32+b] = enc_emb[inp[b][t]], same for decoder.
// ---------------------------------------------------------------------------
__global__ void gather_emb(const int* __restrict__ inp, const int* __restrict__ tar,
                           const u16* __restrict__ enc_emb, const u16* __restrict__ dec_emb,
                           u16* __restrict__ emb_src, u16* __restrict__ dec_e)
{
  int row = blockIdx.x;            // t*32 + b
  int t = row >> 5, b = row & 31;
  int d = blockIdx.y;
  int idx = (d ? tar : inp)[b*64 + t];
  const uint4* src = (const uint4*)((d ? dec_emb : enc_emb) + (size_t)idx*512);
  uint4*       dst = (uint4*)((d ? dec_e : emb_src) + (size_t)row*512);
  dst[threadIdx.x] = src[threadIdx.x];
}

// ---------------------------------------------------------------------------
// Generic MFMA GEMM: C[M,N] = act(A[M,K] * W[N,K]^T + bias). 64x64 tile,
// 4 waves (2x2), 2x2 16x16 frags per wave, direct-global frag loads.
// ---------------------------------------------------------------------------
template<int BIAS, int RELU, typename OutT>
__global__ void __launch_bounds__(256) gemm_bt(
  const u16* __restrict__ A, int lda,
  const u16* __restrict__ W, int ldw,
  const u16* __restrict__ bias,
  OutT* __restrict__ C, int ldc, int K)
{
  int lane = threadIdx.x & 63, w = threadIdx.x >> 6;
  int wm = w >> 1, wn = w & 1;
  int bm = blockIdx.y*64 + wm*32, bn = blockIdx.x*64 + wn*32;
  int q = lane >> 4, col = lane & 15;
  const u16* a0p = A + (size_t)(bm + col)*lda + q*8;
  const u16* a1p = a0p + (size_t)16*lda;
  const u16* b0p = W + (size_t)(bn + col)*ldw + q*8;
  const u16* b1p = b0p + (size_t)16*ldw;
  f32x4 z = {0.f,0.f,0.f,0.f};
  f32x4 acc[2][2] = {{z,z},{z,z}};
  for(int k=0;k<K;k+=32){
    short8 a0 = ld8(a0p + k);
    short8 a1 = ld8(a1p + k);
    short8 b0 = ld8(b0p + k);
    short8 b1 = ld8(b1p + k);
    acc[0][0] = mfma16(a0,b0,acc[0][0]);
    acc[0][1] = mfma16(a0,b1,acc[0][1]);
    acc[1][0] = mfma16(a1,b0,acc[1][0]);
    acc[1][1] = mfma16(a1,b1,acc[1][1]);
  }
  #pragma unroll
  for(int fm=0; fm<2; fm++){
    #pragma unroll
    for(int fn=0; fn<2; fn++){
      int colg = bn + fn*16 + col;
      float bia = BIAS ? bf2f(bias[colg]) : 0.f;
      #pragma unroll
      for(int r=0;r<4;r++){
        int rowg = bm + fm*16 + q*4 + r;   // D: row=(lane>>4)*4+reg, col=lane&15
        float x = acc[fm][fn][r] + bia;
        if(RELU) x = fmaxf(x, 0.f);
        storeC(C, (size_t)rowg*ldc + colg, x);
      }
    }
  }
}

// ---------------------------------------------------------------------------
// PERSISTENT encoder BiLSTM: 64 blocks x 256 threads, 64 steps in-kernel.
// Block (dir, jchunk) owns 16 hidden units of one direction for all steps.
// Grid barrier between steps (h ping-pong). s==0 skips the h-GEMM (h0 = 0).
// ---------------------------------------------------------------------------
#define ENC_NB 64u
__global__ void __launch_bounds__(256) enc_persist(
  const u16* __restrict__ Whh_f, const u16* __restrict__ Whh_b,
  const u16* __restrict__ Xf, const u16* __restrict__ Xb,  // [2048,2048] bf16
  u16* h_enc,                                // [2][2][32][512] bf16 ping-pong
  float* __restrict__ c_enc,                 // [2][32][512] fp32
  u16* __restrict__ enc_out,                 // [64][32][1024] bf16
  u16* __restrict__ A0h, float* __restrict__ c_buf,   // decoder init (s==63)
  unsigned* __restrict__ bar)
{
  int tid = threadIdx.x, lane = tid&63, w = tid>>6;   // w = gate
  int blk = blockIdx.x;
  int dir = blk >> 5, j0 = (blk & 31)*16;
  int q = lane>>4, col = lane&15;
  const u16* W  = dir ? Whh_b : Whh_f;
  const u16* Xp = dir ? Xb : Xf;
  int n = w*512 + j0 + col;
  const u16* wp = W + (size_t)n*512 + q*8;
  __shared__ float gl[4][32][16];

  for(int s=0;s<64;s++){
    int t = dir ? 63 - s : s;
    f32x4 z = {0.f,0.f,0.f,0.f};
    f32x4 acc0=z, acc1=z;
    if(s){
      const u16* hin = h_enc + (size_t)(s&1)*2*32*512;
      const u16* ap = hin + (size_t)(dir*32 + col)*512 + q*8;
      for(int kk=0; kk<512; kk+=32){
        short8 a0 = ld8(ap + kk);
        short8 a1 = ld8(ap + 16*512 + kk);
        short8 b  = ld8(wp + kk);
        acc0 = mfma16(a0,b,acc0); acc1 = mfma16(a1,b,acc1);
      }
    }
    #pragma unroll
    for(int r=0;r<4;r++){
      gl[w][q*4+r][col]    = acc0[r];
      gl[w][16+q*4+r][col] = acc1[r];
    }
    __syncthreads();
    u16* hout = h_enc + (size_t)((s+1)&1)*2*32*512;
    for(int i = tid; i < 512; i += 256){
      int b_ = i>>4, jl = i&15, j = j0 + jl;
      size_t xrow = (size_t)(t*32 + b_)*2048;
      float gi = gl[0][b_][jl] + bf2f(Xp[xrow + j]);
      float gf = gl[1][b_][jl] + bf2f(Xp[xrow + 512 + j]);
      float gg = gl[2][b_][jl] + bf2f(Xp[xrow + 1024 + j]);
      float go = gl[3][b_][jl] + bf2f(Xp[xrow + 1536 + j]);
      int ci = (dir*32 + b_)*512 + j;
      float c = s ? c_enc[ci] : 0.f;
      float cn = sigf(gf)*c + sigf(gi)*tanh_f(gg);
      float hn = sigf(go)*tanh_f(cn);
      c_enc[ci] = cn;
      u16 hb = f2bf(hn);
      hout[(size_t)(dir*32 + b_)*512 + j] = hb;
      enc_out[(size_t)(t*32 + b_)*1024 + dir*512 + j] = hb;
      if(s==63){  // decoder init: h0 = concat(hf,hb), c0 fp32
        A0h[b_*2048 + 1024 + dir*512 + j] = hb;
        c_buf[b_*1024 + dir*512 + j] = cn;
      }
    }
    gbar(bar, ENC_NB);   // step s fully published before step s+1 reads h
  }
}

// ---------------------------------------------------------------------------
// PERSISTENT decoder: 80 blocks x 512 threads, 64 steps x 3 phases.
//  ph1: blocks 0..63  -> h-half of gate GEMM (wave (g,kh): gate g, K-half kh),
//                        accumulators kept in registers into ph3.
//       blocks 64..79 -> hWa1 = h @ Wa1^T (K-split across wave pairs + LDS sum)
//  ph2: blocks 0..31  -> attention (scores/softmax/cvec) for batch b = blk
//  ph3: blocks 0..63  -> cvec-half of gate GEMM (same accs) + fused pointwise
// A ping-pong: Acur = cvec|h of step t; Anext gets h_{t+1}.
// ---------------------------------------------------------------------------
#define DEC_NB 80u
__global__ void __launch_bounds__(512,2) dec_persist(
  u16* A_buf,                          // [2][32][2048] bf16: cvec|h
  const u16* __restrict__ Wa,          // [1024,2048] bf16 (Wa1 cols 0..1023)
  const u16* __restrict__ va,          // [1024]
  const u16* __restrict__ Wih_d,       // [4096,1536]
  const u16* __restrict__ Whh_d,       // [4096,1024]
  const u16* __restrict__ Xd,          // [2048,4096] bf16 (x@Wih_d1^T + b_d)
  const u16* __restrict__ encWa2,      // [2048,1024] bf16
  const u16* __restrict__ enc_out,     // [2048,1024] bf16
  float* __restrict__ hWa1,            // [32,1024] fp32 scratch
  float* __restrict__ c_buf,           // [32,1024] fp32
  u16* __restrict__ hs,                // [32*64,1024] bf16, row = b*64+t
  unsigned* __restrict__ bar)
{
  int tid = threadIdx.x, lane = tid & 63, w = tid >> 6;
  int blk = blockIdx.x;
  int q = lane >> 4, col = lane & 15;
  int g = w & 3, kh = w >> 2;

  __shared__ float gp[2][4][32][16];                  // gate partials / m32 partials
  __shared__ float e_s[1024], va_s[1024], sc_s[64], al_s[64];
  if(blk < 32){ va_s[tid] = bf2f(va[tid]); va_s[tid+512] = bf2f(va[tid+512]); }

  // decoder-gate GEMM config (blocks 0..63): 16 units j0=blk*16, all 4 gates
  int dblk = blk & 63;
  int n = g*1024 + dblk*16 + col;
  const u16* wp1 = Whh_d + (size_t)n*1024 + kh*512 + q*8;          // h-half
  const u16* wp3 = Wih_d + (size_t)n*1536 + 512 + kh*512 + q*8;    // cvec-half
  // hWa1 GEMM config (blocks 64..79): 64 cols each, wave (c4,kh) K-split
  int mb = (blk >= 64) ? (blk - 64) : 0;
  int nm = mb*64 + g*16 + col;                                     // g doubles as c4
  const u16* wpm = Wa + (size_t)nm*2048 + kh*512 + q*8;

  for(int t=0;t<64;t++){
    u16* Acur  = A_buf + (size_t)(t&1)*32*2048;
    u16* Anext = A_buf + (size_t)((t+1)&1)*32*2048;
    f32x4 z = {0.f,0.f,0.f,0.f};
    f32x4 acc0=z, acc1=z;

    // ---------------- phase 1 ----------------
    if(blk < 64){
      const u16* ap = Acur + (size_t)col*2048 + 1024 + kh*512 + q*8;   // h rows
      for(int kk=0; kk<512; kk+=32){
        short8 a0 = ld8(ap + kk);
        short8 a1 = ld8(ap + 16*2048 + kk);
        short8 b  = ld8(wp1 + kk);
        acc0 = mfma16(a0,b,acc0); acc1 = mfma16(a1,b,acc1);
      }
      // accs carried in registers into phase 3
    } else {
      const u16* ap = Acur + (size_t)col*2048 + 1024 + kh*512 + q*8;
      f32x4 m0=z, m1=z;
      for(int kk=0; kk<512; kk+=32){
        short8 a0 = ld8(ap + kk);
        short8 a1 = ld8(ap + 16*2048 + kk);
        short8 b  = ld8(wpm + kk);
        m0 = mfma16(a0,b,m0); m1 = mfma16(a1,b,m1);
      }
      #pragma unroll
      for(int r=0;r<4;r++){
        gp[kh][g][q*4+r][col]    = m0[r];
        gp[kh][g][16+q*4+r][col] = m1[r];
      }
      __syncthreads();
      for(int i=tid; i<2048; i+=512){
        int b_ = i>>6, cc = i&63;
        hWa1[b_*1024 + mb*64 + cc] = gp[0][cc>>4][b_][cc&15] + gp[1][cc>>4][b_][cc&15];
      }
    }
    gbar(bar, DEC_NB);

    // ---------------- phase 2: attention ----------------
    if(blk < 32){
      int b = blk;
      e_s[tid]     = hWa1[b*1024 + tid];
      e_s[tid+512] = hWa1[b*1024 + 512 + tid];
      __syncthreads();
      int grp = tid>>4, l16 = tid&15;
      #pragma unroll
      for(int half=0; half<2; half++){
        int ts = grp + half*32;
        const u16* erow = encWa2 + ((size_t)ts*32 + b)*1024;
        float pacc = 0.f;
        for(int j = l16; j < 1024; j += 16)
          pacc += tanh_f(e_s[j] + bf2f(erow[j])) * va_s[j];
        #pragma unroll
        for(int off=8; off; off>>=1) pacc += __shfl_down(pacc, off, 16);
        if(l16==0) sc_s[ts] = pacc;
      }
      __syncthreads();
      if(tid < 64){
        float sv = sc_s[tid];
        float m = sv;
        #pragma unroll
        for(int off=32; off; off>>=1) m = fmaxf(m, __shfl_xor(m, off, 64));
        float e = __expf(sv - m);
        float ssum = e;
        #pragma unroll
        for(int off=32; off; off>>=1) ssum += __shfl_xor(ssum, off, 64);
        al_s[tid] = e / ssum;
      }
      __syncthreads();
      float cv0 = 0.f, cv1 = 0.f;
      for(int tt=0; tt<64; tt++){
        float a = al_s[tt];
        const u16* er = enc_out + ((size_t)tt*32 + b)*1024;
        cv0 += a * bf2f(er[tid]);
        cv1 += a * bf2f(er[512 + tid]);
      }
      Acur[b*2048 + tid]       = f2bf(cv0);
      Acur[b*2048 + 512 + tid] = f2bf(cv1);
    }
    gbar(bar, DEC_NB);

    // ---------------- phase 3: cvec-half GEMM + pointwise ----------------
    if(blk < 64){
      const u16* ap = Acur + (size_t)col*2048 + kh*512 + q*8;   // cvec rows
      for(int kk=0; kk<512; kk+=32){
        short8 a0 = ld8(ap + kk);
        short8 a1 = ld8(ap + 16*2048 + kk);
        short8 b  = ld8(wp3 + kk);
        acc0 = mfma16(a0,b,acc0); acc1 = mfma16(a1,b,acc1);
      }
      #pragma unroll
      for(int r=0;r<4;r++){
        gp[kh][g][q*4+r][col]    = acc0[r];
        gp[kh][g][16+q*4+r][col] = acc1[r];
      }
      __syncthreads();
      {
        int b_ = tid >> 4, jl = tid & 15, j = dblk*16 + jl;
        size_t xrow = (size_t)(t*32 + b_)*4096;
        float gi = gp[0][0][b_][jl] + gp[1][0][b_][jl] + bf2f(Xd[xrow + j]);
        float gf = gp[0][1][b_][jl] + gp[1][1][b_][jl] + bf2f(Xd[xrow + 1024 + j]);
        float gg = gp[0][2][b_][jl] + gp[1][2][b_][jl] + bf2f(Xd[xrow + 2048 + j]);
        float go = gp[0][3][b_][jl] + gp[1][3][b_][jl] + bf2f(Xd[xrow + 3072 + j]);
        float c = c_buf[b_*1024 + j];
        float cn = sigf(gf)*c + sigf(gi)*tanh_f(gg);
        float hn = sigf(go)*tanh_f(cn);
        c_buf[b_*1024 + j] = cn;
        u16 hb = f2bf(hn);
        Anext[b_*2048 + 1024 + j] = hb;
        hs[(size_t)(b_*64 + t)*1024 + j] = hb;
      }
    }
    gbar(bar, DEC_NB);
  }
}

// ---------------------------------------------------------------------------
// In-place row-wise log_softmax over V=32000 FP32 (after relu'd logits).
// ---------------------------------------------------------------------------
__global__ void __launch_bounds__(256) log_softmax_rows(float* __restrict__ out)
{
  int r = blockIdx.x, tid = threadIdx.x;
  float* row = out + (size_t)r*32000;
  const float4* row4 = (const float4*)row;
  __shared__ float rbuf[16];
  float m = -1e30f;
  for(int c = tid; c < 8000; c += 256){
    float4 u = row4[c];
    m = fmaxf(m, fmaxf(fmaxf(u.x,u.y), fmaxf(u.z,u.w)));
  }
  #pragma unroll
  for(int off=32; off; off>>=1) m = fmaxf(m, __shfl_down(m, off, 64));
  if((tid&63)==0) rbuf[tid>>6] = m;
  __syncthreads();
  if(tid==0) rbuf[8] = fmaxf(fmaxf(rbuf[0],rbuf[1]), fmaxf(rbuf[2],rbuf[3]));
  __syncthreads();
  float M = rbuf[8];
  float s = 0.f;
  for(int c = tid; c < 8000; c += 256){
    float4 u = row4[c];
    s += __expf(u.x-M) + __expf(u.y-M) + __expf(u.z-M) + __expf(u.w-M);
  }
  #pragma unroll
  for(int off=32; off; off>>=1) s += __shfl_down(s, off, 64);
  if((tid&63)==0) rbuf[4 + (tid>>6)] = s;
  __syncthreads();
  if(tid==0) rbuf[9] = M + logf(rbuf[4]+rbuf[5]+rbuf[6]+rbuf[7]);
  __syncthreads();
  float L = rbuf[9];
  float4* row4w = (float4*)row;
  for(int c = tid; c < 8000; c += 256){
    float4 u = row4[c];
    u.x -= L; u.y -= L; u.z -= L; u.w -= L;
    row4w[c] = u;
  }
}

// ---------------------------------------------------------------------------
extern "C" void kernel_launch(void* const* d_in, const int* in_sizes, int n_in,
                              void* d_out, int out_size, void* d_ws, size_t ws_size,
                              hipStream_t stream)
{
  (void)in_sizes; (void)n_in; (void)out_size; (void)ws_size;
  const int* inp     = (const int*)d_in[0];
  const int* tar     = (const int*)d_in[1];
  const u16* enc_emb = (const u16*)d_in[2];
  const u16* dec_emb = (const u16*)d_in[3];
  const u16* Wih_f   = (const u16*)d_in[4];
  const u16* Whh_f   = (const u16*)d_in[5];
  const u16* b_f     = (const u16*)d_in[6];
  const u16* Wih_b   = (const u16*)d_in[7];
  const u16* Whh_b   = (const u16*)d_in[8];
  const u16* b_b     = (const u16*)d_in[9];
  const u16* Wa      = (const u16*)d_in[10];
  const u16* va      = (const u16*)d_in[11];
  const u16* Wih_d   = (const u16*)d_in[12];
  const u16* Whh_d   = (const u16*)d_in[13];
  const u16* b_d     = (const u16*)d_in[14];
  const u16* Wout    = (const u16*)d_in[15];
  const u16* bout    = (const u16*)d_in[16];

  // workspace carve (all 256B aligned); total ~49 MB
  char* p = (char*)d_ws;
  auto carve = [&](size_t bytes)->char*{
    char* r = p; p += (bytes + 255) & ~(size_t)255; return r; };
  u16*   emb_src = (u16*)  carve(2048ull*512*2);
  u16*   dec_e   = (u16*)  carve(2048ull*512*2);
  u16*   Xf      = (u16*)  carve(2048ull*2048*2);
  u16*   Xb      = (u16*)  carve(2048ull*2048*2);
  u16*   Xd      = (u16*)  carve(2048ull*4096*2);
  u16*   enc_out = (u16*)  carve(2048ull*1024*2);
  u16*   encWa2  = (u16*)  carve(2048ull*1024*2);
  u16*   h_enc   = (u16*)  carve(2ull*2*32*512*2);   // 2 ping-pong buffers
  float* c_enc   = (float*)carve(2ull*32*512*4);
  u16*   A_buf   = (u16*)  carve(2ull*32*2048*2);    // 2 ping-pong (cvec|h)
  float* c_buf   = (float*)carve(32ull*1024*4);
  float* hWa1    = (float*)carve(32ull*1024*4);
  u16*   hs      = (u16*)  carve(2048ull*1024*2);
  unsigned* bar  = (unsigned*)carve(256);

  // --- barrier init + embeddings ---
  zero_bar<<<1,64,0,stream>>>(bar);
  gather_emb<<<dim3(2048,2),64,0,stream>>>(inp,tar,enc_emb,dec_emb,emb_src,dec_e);

  // --- input-side gate precompute GEMMs (time-parallel) ---
  gemm_bt<1,0,u16><<<dim3(32,32),256,0,stream>>>(emb_src,512, Wih_f,512,  b_f, Xf,2048, 512);
  gemm_bt<1,0,u16><<<dim3(32,32),256,0,stream>>>(emb_src,512, Wih_b,512,  b_b, Xb,2048, 512);
  gemm_bt<1,0,u16><<<dim3(64,32),256,0,stream>>>(dec_e,  512, Wih_d,1536, b_d, Xd,4096, 512);

  // --- encoder BiLSTM recurrence: ONE persistent kernel (64 steps) ---
  enc_persist<<<64,256,0,stream>>>(Whh_f,Whh_b, Xf,Xb, h_enc, c_enc,
                                   enc_out, A_buf, c_buf, bar);

  // --- decoder-step-invariant attention half: enc_out @ Wa2^T ---
  gemm_bt<0,0,u16><<<dim3(16,32),256,0,stream>>>(enc_out,1024, Wa+1024,2048,
                                                 nullptr, encWa2,1024, 1024);

  // --- decoder: ONE persistent kernel (64 steps x 3 phases) ---
  dec_persist<<<80,512,0,stream>>>(A_buf, Wa, va, Wih_d, Whh_d, Xd,
                                   encWa2, enc_out, hWa1, c_buf, hs, bar);

  // --- output projection + relu (FP32 logits into d_out), then log_softmax ---
  gemm_bt<1,1,float><<<dim3(500,32),256,0,stream>>>(hs,1024, Wout,1024, bout,
                                                    (float*)d_out,32000, 1024);
  log_softmax_rows<<<2048,256,0,stream>>>((float*)d_out);
}

// Round 2
// 7885.133 us; speedup vs baseline: 1.4632x; 1.4632x over previous
//
#include <hip/hip_runtime.h>
#include <stdint.h>
#include <stddef.h>

// ---------------------------------------------------------------------------
// BiLSTM seq2seq (Bahdanau attention) on MI355X.
// B=32, T_src=T_tgt=64, E=512, H=512 (enc dir), dec hidden 2H=1024, V=32000.
// Persistent-kernel recurrences, round 2: FENCE-FREE grid barriers.
// Round-1 lesson (rocprof): agent-scope acquire/release fences invalidate the
// whole per-XCD L2 -> 712 MB HBM re-fetch, 9.1 ms decoder. This revision
// communicates cross-block data (h, cvec, hWa1) via agent-scope RELAXED
// atomics (coherent point = Infinity Cache, no L2 maintenance) and uses a
// barrier with no fences. Weights/Xd/encWa2/enc_out stay plain loads and
// remain L2-resident across all 64 steps.
// ---------------------------------------------------------------------------

using u16 = unsigned short;
using u32 = unsigned int;
using u64 = unsigned long long;
using short8 = __attribute__((ext_vector_type(8))) short;  // 8 bf16 (4 VGPRs)
using f32x4  = __attribute__((ext_vector_type(4))) float;  // MFMA acc

#define DEVI __device__ __forceinline__

DEVI float bf2f(u16 u){ union{u32 i; float f;} v; v.i = ((u32)u)<<16; return v.f; }
DEVI u16 f2bf(float f){ union{float f; u32 i;} v; v.f = f;
  u32 r = (v.i + 0x7fffu + ((v.i>>16)&1u)) >> 16; return (u16)r; }
DEVI float sigf(float x){ x = fminf(fmaxf(x,-30.f),30.f); return 1.f/(1.f+__expf(-x)); }
DEVI float tanh_f(float x){ float ax = fminf(fabsf(x),15.f);
  float e = __expf(2.f*ax); float t = (e-1.f)/(e+1.f); return x<0.f? -t : t; }

DEVI f32x4 mfma16(short8 a, short8 b, f32x4 c){
  return __builtin_amdgcn_mfma_f32_16x16x32_bf16(a,b,c,0,0,0);
}
DEVI short8 ld8(const u16* p){ return *(const short8*)p; }

// Coherent (agent-scope, relaxed) access helpers: go straight to the
// memory-side coherent point; no L2 allocate, no wb/inv.
DEVI short8 ld8c(const u16* p){
  const u64* q = (const u64*)p;
  u64 lo = __hip_atomic_load(q,   __ATOMIC_RELAXED, __HIP_MEMORY_SCOPE_AGENT);
  u64 hi = __hip_atomic_load(q+1, __ATOMIC_RELAXED, __HIP_MEMORY_SCOPE_AGENT);
  union { u64 v[2]; short8 s; } u; u.v[0]=lo; u.v[1]=hi; return u.s;
}
DEVI void st32c(u32* p, u32 v){
  __hip_atomic_store(p, v, __ATOMIC_RELAXED, __HIP_MEMORY_SCOPE_AGENT);
}
DEVI float ldfc(const float* p){
  return __hip_atomic_load(p, __ATOMIC_RELAXED, __HIP_MEMORY_SCOPE_AGENT);
}
DEVI void stfc(float* p, float v){
  __hip_atomic_store(p, v, __ATOMIC_RELAXED, __HIP_MEMORY_SCOPE_AGENT);
}

DEVI void storeC(float* C, size_t i, float v){ C[i]=v; }
DEVI void storeC(u16*   C, size_t i, float v){ C[i]=f2bf(v); }

// ---------------------------------------------------------------------------
// FENCE-FREE device grid barrier (sense-reversing). All communicated data is
// written with agent-scope relaxed atomics (globally visible once vmcnt
// retires); __syncthreads drains vmcnt for every thread before arrival, so
// no release/acquire fences (and no L2 invalidation!) are needed.
// bar[0] = arrival count, bar[1] = generation.
// ---------------------------------------------------------------------------
DEVI void gbar(unsigned* bar, unsigned nb){
  __syncthreads();   // compiler emits s_waitcnt vmcnt(0) lgkmcnt(0) + s_barrier
  if(threadIdx.x==0){
    unsigned g = __hip_atomic_load(bar+1, __ATOMIC_RELAXED, __HIP_MEMORY_SCOPE_AGENT);
    unsigned a = __hip_atomic_fetch_add(bar, 1u, __ATOMIC_RELAXED, __HIP_MEMORY_SCOPE_AGENT);
    if(a == nb-1u){
      __hip_atomic_store(bar, 0u, __ATOMIC_RELAXED, __HIP_MEMORY_SCOPE_AGENT);
      __hip_atomic_fetch_add(bar+1, 1u, __ATOMIC_RELAXED, __HIP_MEMORY_SCOPE_AGENT);
    } else {
      while(__hip_atomic_load(bar+1, __ATOMIC_RELAXED, __HIP_MEMORY_SCOPE_AGENT) == g)
        __builtin_amdgcn_s_sleep(2);
    }
  }
  __syncthreads();
}

__global__ void zero_bar(unsigned* __restrict__ bar){
  if(threadIdx.x < 2) bar[threadIdx.x] = 0u;
}

// ---------------------------------------------------------------------------
// Embedding gather: emb_src[t*32+b] = enc_emb[inp[b][t]], same for decoder.
// ---------------------------------------------------------------------------
__global__ void gather_emb(const int* __restrict__ inp, const int* __restrict__ tar,
                           const u16* __restrict__ enc_emb, const u16* __restrict__ dec_emb,
                           u16* __restrict__ emb_src, u16* __restrict__ dec_e)
{
  int row = blockIdx.x;            // t*32 + b
  int t = row >> 5, b = row & 31;
  int d = blockIdx.y;
  int idx = (d ? tar : inp)[b*64 + t];
  const uint4* src = (const uint4*)((d ? dec_emb : enc_emb) + (size_t)idx*512);
  uint4*       dst = (uint4*)((d ? dec_e : emb_src) + (size_t)row*512);
  dst[threadIdx.x] = src[threadIdx.x];
}

// ---------------------------------------------------------------------------
// Generic MFMA GEMM: C[M,N] = act(A[M,K] * W[N,K]^T + bias). 64x64 tile,
// 4 waves (2x2), 2x2 16x16 frags per wave, direct-global frag loads.
// ---------------------------------------------------------------------------
template<int BIAS, int RELU, typename OutT>
__global__ void __launch_bounds__(256) gemm_bt(
  const u16* __restrict__ A, int lda,
  const u16* __restrict__ W, int ldw,
  const u16* __restrict__ bias,
  OutT* __restrict__ C, int ldc, int K)
{
  int lane = threadIdx.x & 63, w = threadIdx.x >> 6;
  int wm = w >> 1, wn = w & 1;
  int bm = blockIdx.y*64 + wm*32, bn = blockIdx.x*64 + wn*32;
  int q = lane >> 4, col = lane & 15;
  const u16* a0p = A + (size_t)(bm + col)*lda + q*8;
  const u16* a1p = a0p + (size_t)16*lda;
  const u16* b0p = W + (size_t)(bn + col)*ldw + q*8;
  const u16* b1p = b0p + (size_t)16*ldw;
  f32x4 z = {0.f,0.f,0.f,0.f};
  f32x4 acc[2][2] = {{z,z},{z,z}};
  for(int k=0;k<K;k+=32){
    short8 a0 = ld8(a0p + k);
    short8 a1 = ld8(a1p + k);
    short8 b0 = ld8(b0p + k);
    short8 b1 = ld8(b1p + k);
    acc[0][0] = mfma16(a0,b0,acc[0][0]);
    acc[0][1] = mfma16(a0,b1,acc[0][1]);
    acc[1][0] = mfma16(a1,b0,acc[1][0]);
    acc[1][1] = mfma16(a1,b1,acc[1][1]);
  }
  #pragma unroll
  for(int fm=0; fm<2; fm++){
    #pragma unroll
    for(int fn=0; fn<2; fn++){
      int colg = bn + fn*16 + col;
      float bia = BIAS ? bf2f(bias[colg]) : 0.f;
      #pragma unroll
      for(int r=0;r<4;r++){
        int rowg = bm + fm*16 + q*4 + r;   // D: row=(lane>>4)*4+reg, col=lane&15
        float x = acc[fm][fn][r] + bia;
        if(RELU) x = fmaxf(x, 0.f);
        storeC(C, (size_t)rowg*ldc + colg, x);
      }
    }
  }
}

// ---------------------------------------------------------------------------
// PERSISTENT encoder BiLSTM: 64 blocks x 256 threads, 64 steps in-kernel.
// Block (dir, jchunk) owns 16 hidden units of one direction for all steps.
// h ping-pong via coherent atomics; weights stay plain/L2-resident.
// ---------------------------------------------------------------------------
#define ENC_NB 64u
__global__ void __launch_bounds__(256) enc_persist(
  const u16* __restrict__ Whh_f, const u16* __restrict__ Whh_b,
  const u16* __restrict__ Xf, const u16* __restrict__ Xb,  // [2048,2048] bf16
  u16* h_enc,                                // [2][2][32][512] bf16 ping-pong
  float* __restrict__ c_enc,                 // [2][32][512] fp32 (block-private)
  u16* __restrict__ enc_out,                 // [64][32][1024] bf16 (read next kernel)
  u16* __restrict__ A0h, float* __restrict__ c_buf,   // decoder init (s==63)
  unsigned* __restrict__ bar)
{
  int tid = threadIdx.x, lane = tid&63, w = tid>>6;   // w = gate
  int blk = blockIdx.x;
  int dir = blk >> 5, j0 = (blk & 31)*16;
  int q = lane>>4, col = lane&15;
  const u16* W  = dir ? Whh_b : Whh_f;
  const u16* Xp = dir ? Xb : Xf;
  int n = w*512 + j0 + col;
  const u16* wp = W + (size_t)n*512 + q*8;
  __shared__ float gl[4][32][16];

  for(int s=0;s<64;s++){
    int t = dir ? 63 - s : s;
    f32x4 z = {0.f,0.f,0.f,0.f};
    f32x4 acc0=z, acc1=z;
    if(s){
      const u16* hin = h_enc + (size_t)(s&1)*2*32*512;
      const u16* ap = hin + (size_t)(dir*32 + col)*512 + q*8;
      for(int kk=0; kk<512; kk+=32){
        short8 a0 = ld8c(ap + kk);          // h: cross-block -> coherent
        short8 a1 = ld8c(ap + 16*512 + kk);
        short8 b  = ld8(wp + kk);           // weights: plain, L2-resident
        acc0 = mfma16(a0,b,acc0); acc1 = mfma16(a1,b,acc1);
      }
    }
    #pragma unroll
    for(int r=0;r<4;r++){
      gl[w][q*4+r][col]    = acc0[r];
      gl[w][16+q*4+r][col] = acc1[r];
    }
    __syncthreads();
    u16* hout = h_enc + (size_t)((s+1)&1)*2*32*512;
    {
      // 256 threads x 2 adjacent j each = 512 elements (32 batches x 16 units)
      int b_ = tid >> 3, jl = (tid & 7)*2, j = j0 + jl;
      size_t xrow = (size_t)(t*32 + b_)*2048;
      float hnv[2];
      #pragma unroll
      for(int e=0;e<2;e++){
        float gi = gl[0][b_][jl+e] + bf2f(Xp[xrow + j+e]);
        float gf = gl[1][b_][jl+e] + bf2f(Xp[xrow + 512 + j+e]);
        float gg = gl[2][b_][jl+e] + bf2f(Xp[xrow + 1024 + j+e]);
        float go = gl[3][b_][jl+e] + bf2f(Xp[xrow + 1536 + j+e]);
        int ci = (dir*32 + b_)*512 + j+e;
        float c = s ? c_enc[ci] : 0.f;
        float cn = sigf(gf)*c + sigf(gi)*tanh_f(gg);
        hnv[e] = sigf(go)*tanh_f(cn);
        c_enc[ci] = cn;                                   // block-private: plain
        if(s==63) c_buf[b_*1024 + dir*512 + j+e] = cn;    // cross-kernel: plain
      }
      u32 pk = (u32)f2bf(hnv[0]) | ((u32)f2bf(hnv[1])<<16);
      st32c((u32*)(hout + (size_t)(dir*32 + b_)*512 + j), pk);  // cross-block
      *(u32*)(enc_out + (size_t)(t*32 + b_)*1024 + dir*512 + j) = pk;  // cross-kernel
      if(s==63) *(u32*)(A0h + b_*2048 + 1024 + dir*512 + j) = pk;      // cross-kernel
    }
    gbar(bar, ENC_NB);
  }
}

// ---------------------------------------------------------------------------
// PERSISTENT decoder: 80 blocks x 512 threads, 64 steps x 3 phases.
//  ph1: blocks 0..63  -> h-half of gate GEMM (accs stay in registers to ph3)
//       blocks 64..79 -> hWa1 = h @ Wa1^T
//  ph2: blocks 0..31  -> attention (scores/softmax/cvec), b = blk
//  ph3: blocks 0..63  -> cvec-half GEMM (same accs) + fused pointwise
// Cross-block data (A_buf h/cvec, hWa1) via coherent atomics only.
// ---------------------------------------------------------------------------
#define DEC_NB 80u
__global__ void __launch_bounds__(512,2) dec_persist(
  u16* A_buf,                          // [2][32][2048] bf16: cvec|h
  const u16* __restrict__ Wa,          // [1024,2048] bf16 (Wa1 = cols 0..1023)
  const u16* __restrict__ va,          // [1024]
  const u16* __restrict__ Wih_d,       // [4096,1536]
  const u16* __restrict__ Whh_d,       // [4096,1024]
  const u16* __restrict__ Xd,          // [2048,4096] bf16 (x@Wih_d1^T + b_d)
  const u16* __restrict__ encWa2,      // [2048,1024] bf16
  const u16* __restrict__ enc_out,     // [2048,1024] bf16
  float* __restrict__ hWa1,            // [32,1024] fp32 scratch (coherent)
  float* __restrict__ c_buf,           // [32,1024] fp32 (block-private)
  u16* __restrict__ hs,                // [32*64,1024] bf16 (read next kernel)
  unsigned* __restrict__ bar)
{
  int tid = threadIdx.x, lane = tid & 63, w = tid >> 6;
  int blk = blockIdx.x;
  int q = lane >> 4, col = lane & 15;
  int g = w & 3, kh = w >> 2;

  __shared__ float gp[2][4][32][16];
  __shared__ float e_s[1024], va_s[1024], sc_s[64], al_s[64];
  if(blk < 32){ va_s[tid] = bf2f(va[tid]); va_s[tid+512] = bf2f(va[tid+512]); }

  int dblk = blk & 63;
  int n = g*1024 + dblk*16 + col;
  const u16* wp1 = Whh_d + (size_t)n*1024 + kh*512 + q*8;          // h-half
  const u16* wp3 = Wih_d + (size_t)n*1536 + 512 + kh*512 + q*8;    // cvec-half
  int mb = (blk >= 64) ? (blk - 64) : 0;
  int nm = mb*64 + g*16 + col;                                     // g doubles as c4
  const u16* wpm = Wa + (size_t)nm*2048 + kh*512 + q*8;

  for(int t=0;t<64;t++){
    u16* Acur  = A_buf + (size_t)(t&1)*32*2048;
    u16* Anext = A_buf + (size_t)((t+1)&1)*32*2048;
    f32x4 z = {0.f,0.f,0.f,0.f};
    f32x4 acc0=z, acc1=z;

    // ---------------- phase 1 ----------------
    if(blk < 64){
      const u16* ap = Acur + (size_t)col*2048 + 1024 + kh*512 + q*8;   // h rows
      for(int kk=0; kk<512; kk+=32){
        short8 a0 = ld8c(ap + kk);
        short8 a1 = ld8c(ap + 16*2048 + kk);
        short8 b  = ld8(wp1 + kk);
        acc0 = mfma16(a0,b,acc0); acc1 = mfma16(a1,b,acc1);
      }
      // accs carried in registers into phase 3
    } else {
      const u16* ap = Acur + (size_t)col*2048 + 1024 + kh*512 + q*8;
      f32x4 m0=z, m1=z;
      for(int kk=0; kk<512; kk+=32){
        short8 a0 = ld8c(ap + kk);
        short8 a1 = ld8c(ap + 16*2048 + kk);
        short8 b  = ld8(wpm + kk);
        m0 = mfma16(a0,b,m0); m1 = mfma16(a1,b,m1);
      }
      #pragma unroll
      for(int r=0;r<4;r++){
        gp[kh][g][q*4+r][col]    = m0[r];
        gp[kh][g][16+q*4+r][col] = m1[r];
      }
      __syncthreads();
      for(int i=tid; i<2048; i+=512){
        int b_ = i>>6, cc = i&63;
        stfc(&hWa1[b_*1024 + mb*64 + cc],
             gp[0][cc>>4][b_][cc&15] + gp[1][cc>>4][b_][cc&15]);
      }
    }
    gbar(bar, DEC_NB);

    // ---------------- phase 2: attention ----------------
    if(blk < 32){
      int b = blk;
      e_s[tid]     = ldfc(&hWa1[b*1024 + tid]);
      e_s[tid+512] = ldfc(&hWa1[b*1024 + 512 + tid]);
      __syncthreads();
      int grp = tid>>4, l16 = tid&15;
      #pragma unroll
      for(int half=0; half<2; half++){
        int ts = grp + half*32;
        const u16* erow = encWa2 + ((size_t)ts*32 + b)*1024;
        float pacc = 0.f;
        for(int j = l16; j < 1024; j += 16)
          pacc += tanh_f(e_s[j] + bf2f(erow[j])) * va_s[j];
        #pragma unroll
        for(int off=8; off; off>>=1) pacc += __shfl_down(pacc, off, 16);
        if(l16==0) sc_s[ts] = pacc;
      }
      __syncthreads();
      if(tid < 64){
        float sv = sc_s[tid];
        float m = sv;
        #pragma unroll
        for(int off=32; off; off>>=1) m = fmaxf(m, __shfl_xor(m, off, 64));
        float e = __expf(sv - m);
        float ssum = e;
        #pragma unroll
        for(int off=32; off; off>>=1) ssum += __shfl_xor(ssum, off, 64);
        al_s[tid] = e / ssum;
      }
      __syncthreads();
      // 512 threads x 2 adjacent cvec elems -> packed coherent u32 store
      float cv0 = 0.f, cv1 = 0.f;
      const u16* eb = enc_out + (size_t)b*1024 + 2*tid;
      for(int tt=0; tt<64; tt++){
        float a = al_s[tt];
        u32 pr = *(const u32*)(eb + (size_t)tt*32*1024);
        cv0 += a * bf2f((u16)(pr & 0xffff));
        cv1 += a * bf2f((u16)(pr >> 16));
      }
      u32 pk = (u32)f2bf(cv0) | ((u32)f2bf(cv1)<<16);
      st32c((u32*)(Acur + b*2048 + 2*tid), pk);
    }
    gbar(bar, DEC_NB);

    // ---------------- phase 3: cvec-half GEMM + pointwise ----------------
    if(blk < 64){
      const u16* ap = Acur + (size_t)col*2048 + kh*512 + q*8;   // cvec rows
      for(int kk=0; kk<512; kk+=32){
        short8 a0 = ld8c(ap + kk);
        short8 a1 = ld8c(ap + 16*2048 + kk);
        short8 b  = ld8(wp3 + kk);
        acc0 = mfma16(a0,b,acc0); acc1 = mfma16(a1,b,acc1);
      }
      #pragma unroll
      for(int r=0;r<4;r++){
        gp[kh][g][q*4+r][col]    = acc0[r];
        gp[kh][g][16+q*4+r][col] = acc1[r];
      }
      __syncthreads();
      if(tid < 256){
        // 256 threads x 2 adjacent j = 512 elems (32 batches x 16 units)
        int b_ = tid >> 3, jl = (tid & 7)*2, j = dblk*16 + jl;
        size_t xrow = (size_t)(t*32 + b_)*4096;
        float hnv[2];
        #pragma unroll
        for(int e=0;e<2;e++){
          float gi = gp[0][0][b_][jl+e] + gp[1][0][b_][jl+e] + bf2f(Xd[xrow + j+e]);
          float gf = gp[0][1][b_][jl+e] + gp[1][1][b_][jl+e] + bf2f(Xd[xrow + 1024 + j+e]);
          float gg = gp[0][2][b_][jl+e] + gp[1][2][b_][jl+e] + bf2f(Xd[xrow + 2048 + j+e]);
          float go = gp[0][3][b_][jl+e] + gp[1][3][b_][jl+e] + bf2f(Xd[xrow + 3072 + j+e]);
          float c = c_buf[b_*1024 + j+e];
          float cn = sigf(gf)*c + sigf(gi)*tanh_f(gg);
          hnv[e] = sigf(go)*tanh_f(cn);
          c_buf[b_*1024 + j+e] = cn;                     // block-private: plain
        }
        u32 pk = (u32)f2bf(hnv[0]) | ((u32)f2bf(hnv[1])<<16);
        st32c((u32*)(Anext + b_*2048 + 1024 + j), pk);   // cross-block: coherent
        *(u32*)(hs + (size_t)(b_*64 + t)*1024 + j) = pk; // cross-kernel: plain
      }
    }
    gbar(bar, DEC_NB);
  }
}

// ---------------------------------------------------------------------------
// In-place row-wise log_softmax over V=32000 FP32 (after relu'd logits).
// ---------------------------------------------------------------------------
__global__ void __launch_bounds__(256) log_softmax_rows(float* __restrict__ out)
{
  int r = blockIdx.x, tid = threadIdx.x;
  float* row = out + (size_t)r*32000;
  const float4* row4 = (const float4*)row;
  __shared__ float rbuf[16];
  float m = -1e30f;
  for(int c = tid; c < 8000; c += 256){
    float4 u = row4[c];
    m = fmaxf(m, fmaxf(fmaxf(u.x,u.y), fmaxf(u.z,u.w)));
  }
  #pragma unroll
  for(int off=32; off; off>>=1) m = fmaxf(m, __shfl_down(m, off, 64));
  if((tid&63)==0) rbuf[tid>>6] = m;
  __syncthreads();
  if(tid==0) rbuf[8] = fmaxf(fmaxf(rbuf[0],rbuf[1]), fmaxf(rbuf[2],rbuf[3]));
  __syncthreads();
  float M = rbuf[8];
  float s = 0.f;
  for(int c = tid; c < 8000; c += 256){
    float4 u = row4[c];
    s += __expf(u.x-M) + __expf(u.y-M) + __expf(u.z-M) + __expf(u.w-M);
  }
  #pragma unroll
  for(int off=32; off; off>>=1) s += __shfl_down(s, off, 64);
  if((tid&63)==0) rbuf[4 + (tid>>6)] = s;
  __syncthreads();
  if(tid==0) rbuf[9] = M + logf(rbuf[4]+rbuf[5]+rbuf[6]+rbuf[7]);
  __syncthreads();
  float L = rbuf[9];
  float4* row4w = (float4*)row;
  for(int c = tid; c < 8000; c += 256){
    float4 u = row4[c];
    u.x -= L; u.y -= L; u.z -= L; u.w -= L;
    row4w[c] = u;
  }
}

// ---------------------------------------------------------------------------
extern "C" void kernel_launch(void* const* d_in, const int* in_sizes, int n_in,
                              void* d_out, int out_size, void* d_ws, size_t ws_size,
                              hipStream_t stream)
{
  (void)in_sizes; (void)n_in; (void)out_size; (void)ws_size;
  const int* inp     = (const int*)d_in[0];
  const int* tar     = (const int*)d_in[1];
  const u16* enc_emb = (const u16*)d_in[2];
  const u16* dec_emb = (const u16*)d_in[3];
  const u16* Wih_f   = (const u16*)d_in[4];
  const u16* Whh_f   = (const u16*)d_in[5];
  const u16* b_f     = (const u16*)d_in[6];
  const u16* Wih_b   = (const u16*)d_in[7];
  const u16* Whh_b   = (const u16*)d_in[8];
  const u16* b_b     = (const u16*)d_in[9];
  const u16* Wa      = (const u16*)d_in[10];
  const u16* va      = (const u16*)d_in[11];
  const u16* Wih_d   = (const u16*)d_in[12];
  const u16* Whh_d   = (const u16*)d_in[13];
  const u16* b_d     = (const u16*)d_in[14];
  const u16* Wout    = (const u16*)d_in[15];
  const u16* bout    = (const u16*)d_in[16];

  // workspace carve (all 256B aligned); total ~49 MB
  char* p = (char*)d_ws;
  auto carve = [&](size_t bytes)->char*{
    char* r = p; p += (bytes + 255) & ~(size_t)255; return r; };
  u16*   emb_src = (u16*)  carve(2048ull*512*2);
  u16*   dec_e   = (u16*)  carve(2048ull*512*2);
  u16*   Xf      = (u16*)  carve(2048ull*2048*2);
  u16*   Xb      = (u16*)  carve(2048ull*2048*2);
  u16*   Xd      = (u16*)  carve(2048ull*4096*2);
  u16*   enc_out = (u16*)  carve(2048ull*1024*2);
  u16*   encWa2  = (u16*)  carve(2048ull*1024*2);
  u16*   h_enc   = (u16*)  carve(2ull*2*32*512*2);   // 2 ping-pong buffers
  float* c_enc   = (float*)carve(2ull*32*512*4);
  u16*   A_buf   = (u16*)  carve(2ull*32*2048*2);    // 2 ping-pong (cvec|h)
  float* c_buf   = (float*)carve(32ull*1024*4);
  float* hWa1    = (float*)carve(32ull*1024*4);
  u16*   hs      = (u16*)  carve(2048ull*1024*2);
  unsigned* bar  = (unsigned*)carve(256);

  // --- barrier init + embeddings ---
  zero_bar<<<1,64,0,stream>>>(bar);
  gather_emb<<<dim3(2048,2),64,0,stream>>>(inp,tar,enc_emb,dec_emb,emb_src,dec_e);

  // --- input-side gate precompute GEMMs (time-parallel) ---
  gemm_bt<1,0,u16><<<dim3(32,32),256,0,stream>>>(emb_src,512, Wih_f,512,  b_f, Xf,2048, 512);
  gemm_bt<1,0,u16><<<dim3(32,32),256,0,stream>>>(emb_src,512, Wih_b,512,  b_b, Xb,2048, 512);
  gemm_bt<1,0,u16><<<dim3(64,32),256,0,stream>>>(dec_e,  512, Wih_d,1536, b_d, Xd,4096, 512);

  // --- encoder BiLSTM recurrence: ONE persistent kernel (64 steps) ---
  enc_persist<<<64,256,0,stream>>>(Whh_f,Whh_b, Xf,Xb, h_enc, c_enc,
                                   enc_out, A_buf, c_buf, bar);

  // --- decoder-step-invariant attention half: enc_out @ Wa2^T ---
  gemm_bt<0,0,u16><<<dim3(16,32),256,0,stream>>>(enc_out,1024, Wa+1024,2048,
                                                 nullptr, encWa2,1024, 1024);

  // --- decoder: ONE persistent kernel (64 steps x 3 phases) ---
  dec_persist<<<80,512,0,stream>>>(A_buf, Wa, va, Wih_d, Whh_d, Xd,
                                   encWa2, enc_out, hWa1, c_buf, hs, bar);

  // --- output projection + relu (FP32 logits into d_out), then log_softmax ---
  gemm_bt<1,1,float><<<dim3(500,32),256,0,stream>>>(hs,1024, Wout,1024, bout,
                                                    (float*)d_out,32000, 1024);
  log_softmax_rows<<<2048,256,0,stream>>>((float*)d_out);
}

// Round 3
// 6458.272 us; speedup vs baseline: 1.7864x; 1.2209x over previous
//
#include <hip/hip_runtime.h>
#include <stdint.h>
#include <stddef.h>

// ---------------------------------------------------------------------------
// BiLSTM seq2seq (Bahdanau attention) on MI355X.
// B=32, T_src=T_tgt=64, E=512, H=512 (enc dir), dec hidden 2H=1024, V=32000.
// Persistent recurrences, round 3: coherent data STAGED TO LDS.
// Round-2 lesson: agent-scope relaxed atomics are served by Infinity Cache
// (bypass L2); K-loops built from per-fragment IC-latency loads serialize
// (~85 us/step, all pipes idle). This revision stages the small cross-block
// matrices (h 64KB / cvec 64KB / enc-h 32KB) into LDS with one parallel
// coherent burst (16 u64 loads/thread), then feeds MFMA from LDS.
// ---------------------------------------------------------------------------

using u16 = unsigned short;
using u32 = unsigned int;
using u64 = unsigned long long;
using short8 = __attribute__((ext_vector_type(8))) short;  // 8 bf16 (4 VGPRs)
using f32x4  = __attribute__((ext_vector_type(4))) float;  // MFMA acc

#define DEVI __device__ __forceinline__

DEVI float bf2f(u16 u){ union{u32 i; float f;} v; v.i = ((u32)u)<<16; return v.f; }
DEVI u16 f2bf(float f){ union{float f; u32 i;} v; v.f = f;
  u32 r = (v.i + 0x7fffu + ((v.i>>16)&1u)) >> 16; return (u16)r; }
DEVI float sigf(float x){ x = fminf(fmaxf(x,-30.f),30.f); return 1.f/(1.f+__expf(-x)); }
DEVI float tanh_f(float x){ float ax = fminf(fabsf(x),15.f);
  float e = __expf(2.f*ax); float t = (e-1.f)/(e+1.f); return x<0.f? -t : t; }

DEVI f32x4 mfma16(short8 a, short8 b, f32x4 c){
  return __builtin_amdgcn_mfma_f32_16x16x32_bf16(a,b,c,0,0,0);
}
DEVI short8 ld8(const u16* p){ return *(const short8*)p; }

DEVI u64 ld64c(const u64* p){
  return __hip_atomic_load(p, __ATOMIC_RELAXED, __HIP_MEMORY_SCOPE_AGENT);
}
DEVI void st32c(u32* p, u32 v){
  __hip_atomic_store(p, v, __ATOMIC_RELAXED, __HIP_MEMORY_SCOPE_AGENT);
}
DEVI float ldfc(const float* p){
  return __hip_atomic_load(p, __ATOMIC_RELAXED, __HIP_MEMORY_SCOPE_AGENT);
}
DEVI void stfc(float* p, float v){
  __hip_atomic_store(p, v, __ATOMIC_RELAXED, __HIP_MEMORY_SCOPE_AGENT);
}

DEVI void storeC(float* C, size_t i, float v){ C[i]=v; }
DEVI void storeC(u16*   C, size_t i, float v){ C[i]=f2bf(v); }

// ---------------------------------------------------------------------------
// Fence-free device grid barrier (sense-reversing). Communicated data is
// written with agent-scope relaxed atomics (visible at IC once vmcnt
// retires); __syncthreads drains vmcnt before arrival -> no fences, no L2
// invalidation. bar[0] = arrival count, bar[1] = generation.
// ---------------------------------------------------------------------------
DEVI void gbar(unsigned* bar, unsigned nb){
  __syncthreads();
  if(threadIdx.x==0){
    unsigned g = __hip_atomic_load(bar+1, __ATOMIC_RELAXED, __HIP_MEMORY_SCOPE_AGENT);
    unsigned a = __hip_atomic_fetch_add(bar, 1u, __ATOMIC_RELAXED, __HIP_MEMORY_SCOPE_AGENT);
    if(a == nb-1u){
      __hip_atomic_store(bar, 0u, __ATOMIC_RELAXED, __HIP_MEMORY_SCOPE_AGENT);
      __hip_atomic_fetch_add(bar+1, 1u, __ATOMIC_RELAXED, __HIP_MEMORY_SCOPE_AGENT);
    } else {
      while(__hip_atomic_load(bar+1, __ATOMIC_RELAXED, __HIP_MEMORY_SCOPE_AGENT) == g)
        __builtin_amdgcn_s_sleep(2);
    }
  }
  __syncthreads();
}

__global__ void zero_bar(unsigned* __restrict__ bar){
  if(threadIdx.x < 2) bar[threadIdx.x] = 0u;
}

// ---------------------------------------------------------------------------
// Embedding gather.
// ---------------------------------------------------------------------------
__global__ void gather_emb(const int* __restrict__ inp, const int* __restrict__ tar,
                           const u16* __restrict__ enc_emb, const u16* __restrict__ dec_emb,
                           u16* __restrict__ emb_src, u16* __restrict__ dec_e)
{
  int row = blockIdx.x;            // t*32 + b
  int t = row >> 5, b = row & 31;
  int d = blockIdx.y;
  int idx = (d ? tar : inp)[b*64 + t];
  const uint4* src = (const uint4*)((d ? dec_emb : enc_emb) + (size_t)idx*512);
  uint4*       dst = (uint4*)((d ? dec_e : emb_src) + (size_t)row*512);
  dst[threadIdx.x] = src[threadIdx.x];
}

// ---------------------------------------------------------------------------
// Generic MFMA GEMM: C[M,N] = act(A[M,K] * W[N,K]^T + bias). 64x64 tile.
// ---------------------------------------------------------------------------
template<int BIAS, int RELU, typename OutT>
__global__ void __launch_bounds__(256) gemm_bt(
  const u16* __restrict__ A, int lda,
  const u16* __restrict__ W, int ldw,
  const u16* __restrict__ bias,
  OutT* __restrict__ C, int ldc, int K)
{
  int lane = threadIdx.x & 63, w = threadIdx.x >> 6;
  int wm = w >> 1, wn = w & 1;
  int bm = blockIdx.y*64 + wm*32, bn = blockIdx.x*64 + wn*32;
  int q = lane >> 4, col = lane & 15;
  const u16* a0p = A + (size_t)(bm + col)*lda + q*8;
  const u16* a1p = a0p + (size_t)16*lda;
  const u16* b0p = W + (size_t)(bn + col)*ldw + q*8;
  const u16* b1p = b0p + (size_t)16*ldw;
  f32x4 z = {0.f,0.f,0.f,0.f};
  f32x4 acc[2][2] = {{z,z},{z,z}};
  for(int k=0;k<K;k+=32){
    short8 a0 = ld8(a0p + k);
    short8 a1 = ld8(a1p + k);
    short8 b0 = ld8(b0p + k);
    short8 b1 = ld8(b1p + k);
    acc[0][0] = mfma16(a0,b0,acc[0][0]);
    acc[0][1] = mfma16(a0,b1,acc[0][1]);
    acc[1][0] = mfma16(a1,b0,acc[1][0]);
    acc[1][1] = mfma16(a1,b1,acc[1][1]);
  }
  #pragma unroll
  for(int fm=0; fm<2; fm++){
    #pragma unroll
    for(int fn=0; fn<2; fn++){
      int colg = bn + fn*16 + col;
      float bia = BIAS ? bf2f(bias[colg]) : 0.f;
      #pragma unroll
      for(int r=0;r<4;r++){
        int rowg = bm + fm*16 + q*4 + r;   // D: row=(lane>>4)*4+reg, col=lane&15
        float x = acc[fm][fn][r] + bia;
        if(RELU) x = fmaxf(x, 0.f);
        storeC(C, (size_t)rowg*ldc + colg, x);
      }
    }
  }
}

// ---------------------------------------------------------------------------
// PERSISTENT encoder BiLSTM: 64 blocks x 256 threads, 64 steps in-kernel.
// h staged coherent->LDS once per step (32 KB, rows padded to 520 elems for
// bank spread), K-loop fed by ds_read_b128.
// ---------------------------------------------------------------------------
#define ENC_NB 64u
__global__ void __launch_bounds__(256) enc_persist(
  const u16* __restrict__ Whh_f, const u16* __restrict__ Whh_b,
  const u16* __restrict__ Xf, const u16* __restrict__ Xb,  // [2048,2048] bf16
  u16* h_enc,                                // [2][2][32][512] bf16 ping-pong
  float* __restrict__ c_enc,                 // [2][32][512] fp32 (block-private)
  u16* __restrict__ enc_out,                 // [64][32][1024] bf16
  u16* __restrict__ A0h, float* __restrict__ c_buf,   // decoder init (s==63)
  unsigned* __restrict__ bar)
{
  int tid = threadIdx.x, lane = tid&63, w = tid>>6;   // w = gate
  int blk = blockIdx.x;
  int dir = blk >> 5, j0 = (blk & 31)*16;
  int q = lane>>4, col = lane&15;
  const u16* W  = dir ? Whh_b : Whh_f;
  const u16* Xp = dir ? Xb : Xf;
  int n = w*512 + j0 + col;
  const u16* wp = W + (size_t)n*512 + q*8;
  __shared__ u16 h_lds[32][520];     // 32 rows x 512 (+8 pad)
  __shared__ float gl[4][32][16];

  for(int s=0;s<64;s++){
    int t = dir ? 63 - s : s;
    f32x4 z = {0.f,0.f,0.f,0.f};
    f32x4 acc0=z, acc1=z;
    if(s){
      // stage h (this dir, 32x512 bf16 = 32 KB): 16 parallel u64 coherent
      // loads per thread, then LDS writes.
      const u16* hin = h_enc + (size_t)(s&1)*2*32*512 + (size_t)dir*32*512;
      int b_ = tid & 31, kc = tid >> 5;                 // kc in [0,8)
      const u64* srcp = (const u64*)(hin + (size_t)b_*512 + kc*64);
      u64 tmp[16];
      #pragma unroll
      for(int i=0;i<16;i++) tmp[i] = ld64c(srcp + i);
      u64* dstp = (u64*)&h_lds[b_][kc*64];
      #pragma unroll
      for(int i=0;i<16;i++) dstp[i] = tmp[i];
      __syncthreads();
      const u16* apl = &h_lds[col][q*8];
      for(int kk=0; kk<512; kk+=32){
        short8 a0 = ld8(apl + kk);
        short8 a1 = ld8(apl + 16*520 + kk);
        short8 b  = ld8(wp + kk);           // weights: plain, L2-resident
        acc0 = mfma16(a0,b,acc0); acc1 = mfma16(a1,b,acc1);
      }
    }
    #pragma unroll
    for(int r=0;r<4;r++){
      gl[w][q*4+r][col]    = acc0[r];
      gl[w][16+q*4+r][col] = acc1[r];
    }
    __syncthreads();
    u16* hout = h_enc + (size_t)((s+1)&1)*2*32*512;
    {
      int b_ = tid >> 3, jl = (tid & 7)*2, j = j0 + jl;
      size_t xrow = (size_t)(t*32 + b_)*2048;
      float hnv[2];
      #pragma unroll
      for(int e=0;e<2;e++){
        float gi = gl[0][b_][jl+e] + bf2f(Xp[xrow + j+e]);
        float gf = gl[1][b_][jl+e] + bf2f(Xp[xrow + 512 + j+e]);
        float gg = gl[2][b_][jl+e] + bf2f(Xp[xrow + 1024 + j+e]);
        float go = gl[3][b_][jl+e] + bf2f(Xp[xrow + 1536 + j+e]);
        int ci = (dir*32 + b_)*512 + j+e;
        float c = s ? c_enc[ci] : 0.f;
        float cn = sigf(gf)*c + sigf(gi)*tanh_f(gg);
        hnv[e] = sigf(go)*tanh_f(cn);
        c_enc[ci] = cn;                                   // block-private
        if(s==63) c_buf[b_*1024 + dir*512 + j+e] = cn;    // cross-kernel
      }
      u32 pk = (u32)f2bf(hnv[0]) | ((u32)f2bf(hnv[1])<<16);
      st32c((u32*)(hout + (size_t)(dir*32 + b_)*512 + j), pk);  // cross-block
      *(u32*)(enc_out + (size_t)(t*32 + b_)*1024 + dir*512 + j) = pk;
      if(s==63) *(u32*)(A0h + b_*2048 + 1024 + dir*512 + j) = pk;
    }
    gbar(bar, ENC_NB);
  }
}

// ---------------------------------------------------------------------------
// PERSISTENT decoder: 80 blocks x 512 threads, 64 steps x 3 phases.
//  ph1: all blocks stage h (64 KB) -> LDS;
//       blocks 0..63 h-half gate GEMM (accs stay in regs to ph3);
//       blocks 64..79 hWa1 = h @ Wa1^T
//  ph2: blocks 0..31 attention (scores/softmax/cvec), b = blk
//  ph3: blocks 0..63 stage cvec -> LDS, cvec-half GEMM + fused pointwise
// ---------------------------------------------------------------------------
#define DEC_NB 80u
__global__ void __launch_bounds__(512,2) dec_persist(
  u16* A_buf,                          // [2][32][2048] bf16: cvec|h
  const u16* __restrict__ Wa,          // [1024,2048] bf16 (Wa1 = cols 0..1023)
  const u16* __restrict__ va,          // [1024]
  const u16* __restrict__ Wih_d,       // [4096,1536]
  const u16* __restrict__ Whh_d,       // [4096,1024]
  const u16* __restrict__ Xd,          // [2048,4096] bf16 (x@Wih_d1^T + b_d)
  const u16* __restrict__ encWa2,      // [2048,1024] bf16
  const u16* __restrict__ enc_out,     // [2048,1024] bf16
  float* __restrict__ hWa1,            // [32,1024] fp32 scratch (coherent)
  float* __restrict__ c_buf,           // [32,1024] fp32 (block-private)
  u16* __restrict__ hs,                // [32*64,1024] bf16
  unsigned* __restrict__ bar)
{
  int tid = threadIdx.x, lane = tid & 63, w = tid >> 6;
  int blk = blockIdx.x;
  int q = lane >> 4, col = lane & 15;
  int g = w & 3, kh = w >> 2;

  __shared__ u16 A_lds[32][1032];      // staged h or cvec (rows padded +8)
  __shared__ float gp[2][4][32][16];
  __shared__ float e_s[1024], va_s[1024], sc_s[64], al_s[64];
  if(blk < 32){ va_s[tid] = bf2f(va[tid]); va_s[tid+512] = bf2f(va[tid+512]); }

  int dblk = blk & 63;
  int n = g*1024 + dblk*16 + col;
  const u16* wp1 = Whh_d + (size_t)n*1024 + kh*512 + q*8;          // h-half
  const u16* wp3 = Wih_d + (size_t)n*1536 + 512 + kh*512 + q*8;    // cvec-half
  int mb = (blk >= 64) ? (blk - 64) : 0;
  int nm = mb*64 + g*16 + col;                                     // g doubles as c4
  const u16* wpm = Wa + (size_t)nm*2048 + kh*512 + q*8;

  // stage 32x1024 bf16 (64 KB) from coherent A_buf region into A_lds:
  // thread (b_=tid&31, kc=tid>>5 in [0,16)) loads 64 contiguous elems.
  auto stageA = [&](const u16* srcbase){
    int b_ = tid & 31, kc = tid >> 5;
    const u64* srcp = (const u64*)(srcbase + (size_t)b_*2048 + kc*64);
    u64 tmp[16];
    #pragma unroll
    for(int i=0;i<16;i++) tmp[i] = ld64c(srcp + i);
    u64* dstp = (u64*)&A_lds[b_][kc*64];
    #pragma unroll
    for(int i=0;i<16;i++) dstp[i] = tmp[i];
  };

  for(int t=0;t<64;t++){
    u16* Acur  = A_buf + (size_t)(t&1)*32*2048;
    u16* Anext = A_buf + (size_t)((t+1)&1)*32*2048;
    f32x4 z = {0.f,0.f,0.f,0.f};
    f32x4 acc0=z, acc1=z;

    // ---------------- phase 1: h-GEMMs (from LDS) ----------------
    stageA(Acur + 1024);               // h rows
    __syncthreads();
    const u16* apl = &A_lds[col][kh*512 + q*8];
    if(blk < 64){
      for(int kk=0; kk<512; kk+=32){
        short8 a0 = ld8(apl + kk);
        short8 a1 = ld8(apl + 16*1032 + kk);
        short8 b  = ld8(wp1 + kk);
        acc0 = mfma16(a0,b,acc0); acc1 = mfma16(a1,b,acc1);
      }
      // accs carried in registers into phase 3
    } else {
      f32x4 m0=z, m1=z;
      for(int kk=0; kk<512; kk+=32){
        short8 a0 = ld8(apl + kk);
        short8 a1 = ld8(apl + 16*1032 + kk);
        short8 b  = ld8(wpm + kk);
        m0 = mfma16(a0,b,m0); m1 = mfma16(a1,b,m1);
      }
      #pragma unroll
      for(int r=0;r<4;r++){
        gp[kh][g][q*4+r][col]    = m0[r];
        gp[kh][g][16+q*4+r][col] = m1[r];
      }
      __syncthreads();
      for(int i=tid; i<2048; i+=512){
        int b_ = i>>6, cc = i&63;
        stfc(&hWa1[b_*1024 + mb*64 + cc],
             gp[0][cc>>4][b_][cc&15] + gp[1][cc>>4][b_][cc&15]);
      }
    }
    gbar(bar, DEC_NB);

    // ---------------- phase 2: attention ----------------
    if(blk < 32){
      int b = blk;
      e_s[tid]     = ldfc(&hWa1[b*1024 + tid]);
      e_s[tid+512] = ldfc(&hWa1[b*1024 + 512 + tid]);
      __syncthreads();
      int grp = tid>>4, l16 = tid&15;
      #pragma unroll
      for(int half=0; half<2; half++){
        int ts = grp + half*32;
        const u16* erow = encWa2 + ((size_t)ts*32 + b)*1024;
        float pacc = 0.f;
        for(int j = l16; j < 1024; j += 16)
          pacc += tanh_f(e_s[j] + bf2f(erow[j])) * va_s[j];
        #pragma unroll
        for(int off=8; off; off>>=1) pacc += __shfl_down(pacc, off, 16);
        if(l16==0) sc_s[ts] = pacc;
      }
      __syncthreads();
      if(tid < 64){
        float sv = sc_s[tid];
        float m = sv;
        #pragma unroll
        for(int off=32; off; off>>=1) m = fmaxf(m, __shfl_xor(m, off, 64));
        float e = __expf(sv - m);
        float ssum = e;
        #pragma unroll
        for(int off=32; off; off>>=1) ssum += __shfl_xor(ssum, off, 64);
        al_s[tid] = e / ssum;
      }
      __syncthreads();
      float cv0 = 0.f, cv1 = 0.f;
      const u16* eb = enc_out + (size_t)b*1024 + 2*tid;
      for(int tt=0; tt<64; tt++){
        float a = al_s[tt];
        u32 pr = *(const u32*)(eb + (size_t)tt*32*1024);
        cv0 += a * bf2f((u16)(pr & 0xffff));
        cv1 += a * bf2f((u16)(pr >> 16));
      }
      u32 pk = (u32)f2bf(cv0) | ((u32)f2bf(cv1)<<16);
      st32c((u32*)(Acur + b*2048 + 2*tid), pk);
    }
    gbar(bar, DEC_NB);

    // ---------------- phase 3: cvec-half GEMM + pointwise ----------------
    if(blk < 64){
      stageA(Acur);                    // cvec rows
      __syncthreads();
      for(int kk=0; kk<512; kk+=32){
        short8 a0 = ld8(apl + kk);
        short8 a1 = ld8(apl + 16*1032 + kk);
        short8 b  = ld8(wp3 + kk);
        acc0 = mfma16(a0,b,acc0); acc1 = mfma16(a1,b,acc1);
      }
      #pragma unroll
      for(int r=0;r<4;r++){
        gp[kh][g][q*4+r][col]    = acc0[r];
        gp[kh][g][16+q*4+r][col] = acc1[r];
      }
      __syncthreads();
      if(tid < 256){
        int b_ = tid >> 3, jl = (tid & 7)*2, j = dblk*16 + jl;
        size_t xrow = (size_t)(t*32 + b_)*4096;
        float hnv[2];
        #pragma unroll
        for(int e=0;e<2;e++){
          float gi = gp[0][0][b_][jl+e] + gp[1][0][b_][jl+e] + bf2f(Xd[xrow + j+e]);
          float gf = gp[0][1][b_][jl+e] + gp[1][1][b_][jl+e] + bf2f(Xd[xrow + 1024 + j+e]);
          float gg = gp[0][2][b_][jl+e] + gp[1][2][b_][jl+e] + bf2f(Xd[xrow + 2048 + j+e]);
          float go = gp[0][3][b_][jl+e] + gp[1][3][b_][jl+e] + bf2f(Xd[xrow + 3072 + j+e]);
          float c = c_buf[b_*1024 + j+e];
          float cn = sigf(gf)*c + sigf(gi)*tanh_f(gg);
          hnv[e] = sigf(go)*tanh_f(cn);
          c_buf[b_*1024 + j+e] = cn;                     // block-private
        }
        u32 pk = (u32)f2bf(hnv[0]) | ((u32)f2bf(hnv[1])<<16);
        st32c((u32*)(Anext + b_*2048 + 1024 + j), pk);   // cross-block
        *(u32*)(hs + (size_t)(b_*64 + t)*1024 + j) = pk; // cross-kernel
      }
    }
    gbar(bar, DEC_NB);
  }
}

// ---------------------------------------------------------------------------
// In-place row-wise log_softmax over V=32000 FP32.
// ---------------------------------------------------------------------------
__global__ void __launch_bounds__(256) log_softmax_rows(float* __restrict__ out)
{
  int r = blockIdx.x, tid = threadIdx.x;
  float* row = out + (size_t)r*32000;
  const float4* row4 = (const float4*)row;
  __shared__ float rbuf[16];
  float m = -1e30f;
  for(int c = tid; c < 8000; c += 256){
    float4 u = row4[c];
    m = fmaxf(m, fmaxf(fmaxf(u.x,u.y), fmaxf(u.z,u.w)));
  }
  #pragma unroll
  for(int off=32; off; off>>=1) m = fmaxf(m, __shfl_down(m, off, 64));
  if((tid&63)==0) rbuf[tid>>6] = m;
  __syncthreads();
  if(tid==0) rbuf[8] = fmaxf(fmaxf(rbuf[0],rbuf[1]), fmaxf(rbuf[2],rbuf[3]));
  __syncthreads();
  float M = rbuf[8];
  float s = 0.f;
  for(int c = tid; c < 8000; c += 256){
    float4 u = row4[c];
    s += __expf(u.x-M) + __expf(u.y-M) + __expf(u.z-M) + __expf(u.w-M);
  }
  #pragma unroll
  for(int off=32; off; off>>=1) s += __shfl_down(s, off, 64);
  if((tid&63)==0) rbuf[4 + (tid>>6)] = s;
  __syncthreads();
  if(tid==0) rbuf[9] = M + logf(rbuf[4]+rbuf[5]+rbuf[6]+rbuf[7]);
  __syncthreads();
  float L = rbuf[9];
  float4* row4w = (float4*)row;
  for(int c = tid; c < 8000; c += 256){
    float4 u = row4[c];
    u.x -= L; u.y -= L; u.z -= L; u.w -= L;
    row4w[c] = u;
  }
}

// ---------------------------------------------------------------------------
extern "C" void kernel_launch(void* const* d_in, const int* in_sizes, int n_in,
                              void* d_out, int out_size, void* d_ws, size_t ws_size,
                              hipStream_t stream)
{
  (void)in_sizes; (void)n_in; (void)out_size; (void)ws_size;
  const int* inp     = (const int*)d_in[0];
  const int* tar     = (const int*)d_in[1];
  const u16* enc_emb = (const u16*)d_in[2];
  const u16* dec_emb = (const u16*)d_in[3];
  const u16* Wih_f   = (const u16*)d_in[4];
  const u16* Whh_f   = (const u16*)d_in[5];
  const u16* b_f     = (const u16*)d_in[6];
  const u16* Wih_b   = (const u16*)d_in[7];
  const u16* Whh_b   = (const u16*)d_in[8];
  const u16* b_b     = (const u16*)d_in[9];
  const u16* Wa      = (const u16*)d_in[10];
  const u16* va      = (const u16*)d_in[11];
  const u16* Wih_d   = (const u16*)d_in[12];
  const u16* Whh_d   = (const u16*)d_in[13];
  const u16* b_d     = (const u16*)d_in[14];
  const u16* Wout    = (const u16*)d_in[15];
  const u16* bout    = (const u16*)d_in[16];

  // workspace carve (all 256B aligned); total ~49 MB
  char* p = (char*)d_ws;
  auto carve = [&](size_t bytes)->char*{
    char* r = p; p += (bytes + 255) & ~(size_t)255; return r; };
  u16*   emb_src = (u16*)  carve(2048ull*512*2);
  u16*   dec_e   = (u16*)  carve(2048ull*512*2);
  u16*   Xf      = (u16*)  carve(2048ull*2048*2);
  u16*   Xb      = (u16*)  carve(2048ull*2048*2);
  u16*   Xd      = (u16*)  carve(2048ull*4096*2);
  u16*   enc_out = (u16*)  carve(2048ull*1024*2);
  u16*   encWa2  = (u16*)  carve(2048ull*1024*2);
  u16*   h_enc   = (u16*)  carve(2ull*2*32*512*2);   // 2 ping-pong buffers
  float* c_enc   = (float*)carve(2ull*32*512*4);
  u16*   A_buf   = (u16*)  carve(2ull*32*2048*2);    // 2 ping-pong (cvec|h)
  float* c_buf   = (float*)carve(32ull*1024*4);
  float* hWa1    = (float*)carve(32ull*1024*4);
  u16*   hs      = (u16*)  carve(2048ull*1024*2);
  unsigned* bar  = (unsigned*)carve(256);

  // --- barrier init + embeddings ---
  zero_bar<<<1,64,0,stream>>>(bar);
  gather_emb<<<dim3(2048,2),64,0,stream>>>(inp,tar,enc_emb,dec_emb,emb_src,dec_e);

  // --- input-side gate precompute GEMMs (time-parallel) ---
  gemm_bt<1,0,u16><<<dim3(32,32),256,0,stream>>>(emb_src,512, Wih_f,512,  b_f, Xf,2048, 512);
  gemm_bt<1,0,u16><<<dim3(32,32),256,0,stream>>>(emb_src,512, Wih_b,512,  b_b, Xb,2048, 512);
  gemm_bt<1,0,u16><<<dim3(64,32),256,0,stream>>>(dec_e,  512, Wih_d,1536, b_d, Xd,4096, 512);

  // --- encoder BiLSTM recurrence: ONE persistent kernel (64 steps) ---
  enc_persist<<<64,256,0,stream>>>(Whh_f,Whh_b, Xf,Xb, h_enc, c_enc,
                                   enc_out, A_buf, c_buf, bar);

  // --- decoder-step-invariant attention half: enc_out @ Wa2^T ---
  gemm_bt<0,0,u16><<<dim3(16,32),256,0,stream>>>(enc_out,1024, Wa+1024,2048,
                                                 nullptr, encWa2,1024, 1024);

  // --- decoder: ONE persistent kernel (64 steps x 3 phases) ---
  dec_persist<<<80,512,0,stream>>>(A_buf, Wa, va, Wih_d, Whh_d, Xd,
                                   encWa2, enc_out, hWa1, c_buf, hs, bar);

  // --- output projection + relu (FP32 logits into d_out), then log_softmax ---
  gemm_bt<1,1,float><<<dim3(500,32),256,0,stream>>>(hs,1024, Wout,1024, bout,
                                                    (float*)d_out,32000, 1024);
  log_softmax_rows<<<2048,256,0,stream>>>((float*)d_out);
}